// Round 7
// baseline (385.128 us; speedup 1.0000x reference)
//
#include <hip/hip_runtime.h>
#include <hip/hip_bf16.h>

#define NN 6000
#define EE 192000

// ---------------- workspace layout (in 4-byte words) ----------------
#define W_DEG     0
#define W_CUR     6000
#define W_STATS   12000        // 6 slots x 128 (sum[64], sumsq[64])
#define W_SXACC   12768        // 4 x 192
#define W_ZEND    13536
#define W_FLAG    13536
#define W_ROWPTR  13540        // 6001
#define W_COL     19544        // 192000
#define W_X0      211544       // 6000*64
#define W_ZP1     595544
#define W_ZP2     979544
#define W_ZP3     1363544      // 6000*4
#define W_ZE1     1387544
#define W_ZE2     1771544
#define W_ZE3     2155544
#define W_S       2539544      // 6000*4
#define W_SX2     2563544      // 64
#define W_PAR     2563608      // fp32 param region

struct PtrTab {
  const void* src[29];
  int off[29];
  int cnt[29];
};

__device__ __forceinline__ float bf2f(unsigned short h) {
  return __uint_as_float(((unsigned)h) << 16);
}
__device__ __forceinline__ int rfl(int x) { return __builtin_amdgcn_readfirstlane(x); }

// ---- fused prelude: dtype detect (per-block, redundant) + param convert +
// embedding gather (inline dtype) + degree count. 1154 blocks:
// [0,29) convert, [29,404) emb, [404,1154) deg.
__global__ __launch_bounds__(256) void k_prelude(
    PtrTab tab, float* __restrict__ base,
    const int* __restrict__ nt, float* __restrict__ x0,
    const int* __restrict__ ei, int* __restrict__ deg, int* __restrict__ flag) {
  __shared__ int s_ok;
  int tid = threadIdx.x;
  const unsigned short* ep = (const unsigned short*)tab.src[0];
  if (tid == 0) s_ok = 1;
  __syncthreads();
  float v0 = bf2f(ep[tid]), v1 = bf2f(ep[tid + 256]);
  if (!(fabsf(v0) <= 100.f) || !(fabsf(v1) <= 100.f)) atomicAnd(&s_ok, 0);
  __syncthreads();
  bool bf = (s_ok != 0);
  int b = blockIdx.x;
  if (b == 0 && tid == 0) flag[0] = bf ? 1 : 0;

  if (b < 29) {
    const void* s = tab.src[b];
    float* d = base + tab.off[b];
    int n = tab.cnt[b];
    if (bf) {
      const unsigned short* sp = (const unsigned short*)s;
      for (int i = tid; i < n; i += 256) d[i] = bf2f(sp[i]);
    } else {
      const float* sp = (const float*)s;
      for (int i = tid; i < n; i += 256) d[i] = sp[i];
    }
  } else if (b < 404) {
    int t = (b - 29) * 256 + tid;            // 96000 threads
    int i = t >> 4, q = t & 15;
    int row = nt[i];
    if (bf) {
      const unsigned short* sp = (const unsigned short*)tab.src[0] + row * 64 + q * 4;
      float4 o;
      o.x = bf2f(sp[0]); o.y = bf2f(sp[1]); o.z = bf2f(sp[2]); o.w = bf2f(sp[3]);
      *(float4*)&x0[i * 64 + q * 4] = o;
    } else {
      *(float4*)&x0[i * 64 + q * 4] =
          *(const float4*)((const float*)tab.src[0] + row * 64 + q * 4);
    }
  } else {
    int e = (b - 404) * 256 + tid;
    if (e < EE) atomicAdd(&deg[ei[e]], 1);
  }
}

__global__ void k_scan(const int* __restrict__ deg, int* __restrict__ rowptr) {
  __shared__ int part[1024];
  int t = threadIdx.x;
  int base = t * 6;
  int loc[6]; int s = 0;
#pragma unroll
  for (int j = 0; j < 6; ++j) { int i = base + j; int v = (i < NN) ? deg[i] : 0; loc[j] = s; s += v; }
  part[t] = s;
  __syncthreads();
  for (int off = 1; off < 1024; off <<= 1) {
    int v = part[t];
    int add = (t >= off) ? part[t - off] : 0;
    __syncthreads();
    part[t] = v + add;
    __syncthreads();
  }
  int pre = (t == 0) ? 0 : part[t - 1];
#pragma unroll
  for (int j = 0; j < 6; ++j) { int i = base + j; if (i <= NN) rowptr[i] = pre + loc[j]; }
}

__global__ void k_scatter(const int* __restrict__ ei, const int* __restrict__ rowptr,
                          int* __restrict__ cur, int* __restrict__ col) {
  int e = blockIdx.x * 256 + threadIdx.x;
  if (e < EE) {
    int s = ei[e], d = ei[EE + e];
    int pos = atomicAdd(&cur[s], 1);
    col[rowptr[s] + pos] = d;
  }
}

// ---- fused DenseSAGE body: feature-per-lane gather (round-3 structure) with
// SPLIT DEPENDENCY CHAINS: 4 partial gather sums + 4 partial MAC accumulators.
// Round-6 evidence: DS pipe was never the limit; the serial FMA/add chains were
// (~768 cy/node of pure dependent latency). Splitting 4-ways cuts that ~4x.
template <int OUT, bool HS>
__device__ __forceinline__ void sage_body(
    const float* __restrict__ in_z, const float* __restrict__ in_stats,
    const float* __restrict__ wr, const float* __restrict__ wl, const float* __restrict__ bias,
    const int* __restrict__ rowptr, const int* __restrict__ col,
    float* __restrict__ out_z, float* __restrict__ out_stats,
    int vb, int total_waves,
    float* __restrict__ wrT, float* __restrict__ wlT, float* __restrict__ bs,
    float (* __restrict__ vec)[2][64], float (* __restrict__ red)[2][64]) {
  int tid = threadIdx.x, lane = tid & 63, wv = tid >> 6;

  for (int i = tid; i < 64 * OUT; i += 256) {
    int f = i >> 6, k = i & 63;                 // w row-major [OUT][64]: row f, col k
    wrT[k * (OUT + 1) + f] = wr[i];             // transposed + padded: conflict-free
    wlT[k * (OUT + 1) + f] = wl[i];
  }
  if (tid < OUT) bs[tid] = bias[tid];

  float m = 0.f, r = 1.f;
  if (HS) {
    float s = in_stats[lane], q = in_stats[64 + lane];
    m = s * (1.f / NN);
    r = rsqrtf(q * (1.f / NN) - m * m + 1e-5f);
  }
  __syncthreads();   // weights staged; no further barriers until epilogue

  float accs = 0.f, accq = 0.f;
  int ol = lane & (OUT - 1);
  int wave_id = vb * 4 + wv;
  for (int n = wave_id; n < NN; n += total_waves) {
    float x = (in_z[n * 64 + lane] - m) * r;
    int rs = rfl(rowptr[n]), re = rfl(rowptr[n + 1]);
    int cnt = re - rs;
    float szA = 0.f, szB = 0.f, szC = 0.f, szD = 0.f;   // 4-way split reduce chain
    for (int base = rs; base < re; base += 64) {
      int ci = base + lane;
      int colv = col[ci < re ? ci : (re - 1)];   // clamped: lanes >= count hold a valid row
      int full = re - base; if (full > 64) full = 64;  // uniform
      int ng8 = (full + 7) >> 3;
      for (int g = 0; g < ng8; ++g) {
        int e0 = g * 8;
#pragma unroll
        for (int u = 0; u < 8; ++u) {
          int j = __builtin_amdgcn_readlane(colv, e0 + u);   // uniform SGPR
          float v = in_z[j * 64 + lane];                      // coalesced 256B wave load
          float vv = (e0 + u < full) ? v : 0.f;               // uniform cndmask
          if ((u & 3) == 0) szA += vv;
          else if ((u & 3) == 1) szB += vv;
          else if ((u & 3) == 2) szC += vv;
          else szD += vv;
        }
      }
    }
    float sz = (szA + szB) + (szC + szD);
    float fc = (float)cnt;
    float inv = 1.f / (float)(cnt > 0 ? cnt : 1);
    float a = (sz - fc * m) * r * inv;           // mean of normalized neighbors
    vec[wv][0][lane] = a;
    vec[wv][1][lane] = x;
    // wave-synchronous LDS write->read (in-order DS pipe within a wave)
    float y0 = bs[ol], y1 = 0.f, y2 = 0.f, y3 = 0.f;   // 4-way split MAC chain
    const float* va = &vec[wv][0][0];
    const float* vx = &vec[wv][1][0];
#pragma unroll
    for (int kk = 0; kk < 16; ++kk) {
      const float4 a4 = *(const float4*)(va + kk * 4);   // broadcast
      const float4 x4 = *(const float4*)(vx + kk * 4);
      int k0 = kk * 4;
      y0 += a4.x * wrT[(k0 + 0) * (OUT + 1) + ol] + x4.x * wlT[(k0 + 0) * (OUT + 1) + ol];
      y1 += a4.y * wrT[(k0 + 1) * (OUT + 1) + ol] + x4.y * wlT[(k0 + 1) * (OUT + 1) + ol];
      y2 += a4.z * wrT[(k0 + 2) * (OUT + 1) + ol] + x4.z * wlT[(k0 + 2) * (OUT + 1) + ol];
      y3 += a4.w * wrT[(k0 + 3) * (OUT + 1) + ol] + x4.w * wlT[(k0 + 3) * (OUT + 1) + ol];
    }
    float y = (y0 + y1) + (y2 + y3);
    float z = fmaxf(y, 0.f);
    if (lane < OUT) {
      out_z[n * OUT + lane] = z;
      accs += z; accq += z * z;
    }
  }
  if (lane < OUT) { red[wv][0][lane] = accs; red[wv][1][lane] = accq; }
  __syncthreads();
  if (tid < OUT) {
    float s = red[0][0][tid] + red[1][0][tid] + red[2][0][tid] + red[3][0][tid];
    float q = red[0][1][tid] + red[1][1][tid] + red[2][1][tid] + red[3][1][tid];
    atomicAdd(&out_stats[tid], s);
    atomicAdd(&out_stats[64 + tid], q);
  }
}

// dual-path sage, XCD-partitioned: blocks land on XCD (blockIdx % 8) round-robin.
// XCDs 0-3 run path A, XCDs 4-7 run path B, so each XCD's 4 MiB L2 only holds
// ONE path's working set (in 1.5 MB + col 0.77 MB) -> gathers hit L2.
template <int OUTA, int OUTB, bool HS>
__global__ __launch_bounds__(256, 4) void k_dual(
    const float* __restrict__ inA, const float* __restrict__ stA,
    const float* __restrict__ wrA, const float* __restrict__ wlA, const float* __restrict__ bA,
    float* __restrict__ outA, float* __restrict__ ostA,
    const float* __restrict__ inB, const float* __restrict__ stB,
    const float* __restrict__ wrB, const float* __restrict__ wlB, const float* __restrict__ bB,
    float* __restrict__ outB, float* __restrict__ ostB,
    const int* __restrict__ rowptr, const int* __restrict__ col, int G) {
  __shared__ float wrT[64 * 65];
  __shared__ float wlT[64 * 65];
  __shared__ float bs[64];
  __shared__ float vec[4][2][64];
  __shared__ float red[4][2][64];
  int bx = (int)blockIdx.x;
  int hi = (bx >> 2) & 1;                 // XCD 0-3 -> path A, XCD 4-7 -> path B
  int vb = (bx >> 3) * 4 + (bx & 3);      // 0..G-1 within the path
  if (hi == 0)
    sage_body<OUTA, HS>(inA, stA, wrA, wlA, bA, rowptr, col, outA, ostA,
                        vb, G * 4, wrT, wlT, bs, vec, red);
  else
    sage_body<OUTB, HS>(inB, stB, wrB, wlB, bB, rowptr, col, outB, ostB,
                        vb, G * 4, wrT, wlT, bs, vec, red);
}

// ---- pool head: grid 375 blocks, 4 nodes per wave ----
__global__ __launch_bounds__(256) void k_pool(
    const float* __restrict__ zp1, const float* __restrict__ zp2, const float* __restrict__ zp3,
    const float* __restrict__ sp1, const float* __restrict__ sp2, const float* __restrict__ sp3,
    const float* __restrict__ ze1, const float* __restrict__ ze2, const float* __restrict__ ze3,
    const float* __restrict__ se1, const float* __restrict__ se2, const float* __restrict__ se3,
    const float* __restrict__ plw, const float* __restrict__ plb,
    float* __restrict__ s_out, float* __restrict__ sx_acc) {
  __shared__ float red[4][12][64];
  int tid = threadIdx.x, lane = tid & 63, wv = tid >> 6;

  float mp1 = sp1[lane] * (1.f / NN); float rp1 = rsqrtf(sp1[64 + lane] * (1.f / NN) - mp1 * mp1 + 1e-5f);
  float mp2 = sp2[lane] * (1.f / NN); float rp2 = rsqrtf(sp2[64 + lane] * (1.f / NN) - mp2 * mp2 + 1e-5f);
  float mp3 = 0.f, rp3 = 1.f;
  if (lane < 4) { mp3 = sp3[lane] * (1.f / NN); rp3 = rsqrtf(sp3[64 + lane] * (1.f / NN) - mp3 * mp3 + 1e-5f); }
  float me1 = se1[lane] * (1.f / NN); float re1 = rsqrtf(se1[64 + lane] * (1.f / NN) - me1 * me1 + 1e-5f);
  float me2 = se2[lane] * (1.f / NN); float re2 = rsqrtf(se2[64 + lane] * (1.f / NN) - me2 * me2 + 1e-5f);
  float me3 = se3[lane] * (1.f / NN); float re3 = rsqrtf(se3[64 + lane] * (1.f / NN) - me3 * me3 + 1e-5f);

  float w0a = plw[0 * 132 + lane], w0b = plw[0 * 132 + 64 + lane], w0c = (lane < 4) ? plw[0 * 132 + 128 + lane] : 0.f;
  float w1a = plw[1 * 132 + lane], w1b = plw[1 * 132 + 64 + lane], w1c = (lane < 4) ? plw[1 * 132 + 128 + lane] : 0.f;
  float w2a = plw[2 * 132 + lane], w2b = plw[2 * 132 + 64 + lane], w2c = (lane < 4) ? plw[2 * 132 + 128 + lane] : 0.f;
  float w3a = plw[3 * 132 + lane], w3b = plw[3 * 132 + 64 + lane], w3c = (lane < 4) ? plw[3 * 132 + 128 + lane] : 0.f;
  float pb0 = plb[0], pb1v = plb[1], pb2v = plb[2], pb3v = plb[3];

  float acc[12];
#pragma unroll
  for (int u = 0; u < 12; ++u) acc[u] = 0.f;

  int wave_id = blockIdx.x * 4 + wv;       // 0..1499
  for (int n = wave_id; n < NN; n += 1500) {
    float a = (zp1[n * 64 + lane] - mp1) * rp1;
    float b = (zp2[n * 64 + lane] - mp2) * rp2;
    float c = (lane < 4) ? ((zp3[n * 4 + lane] - mp3) * rp3) : 0.f;
    float p0 = a * w0a + b * w0b + c * w0c;
    float p1 = a * w1a + b * w1b + c * w1c;
    float p2 = a * w2a + b * w2b + c * w2c;
    float p3 = a * w3a + b * w3b + c * w3c;
#pragma unroll
    for (int off = 1; off < 64; off <<= 1) {
      p0 += __shfl_xor(p0, off);
      p1 += __shfl_xor(p1, off);
      p2 += __shfl_xor(p2, off);
      p3 += __shfl_xor(p3, off);
    }
    float s0 = fmaxf(p0 + pb0, 0.f), s1 = fmaxf(p1 + pb1v, 0.f);
    float s2 = fmaxf(p2 + pb2v, 0.f), s3 = fmaxf(p3 + pb3v, 0.f);
    if (lane < 4) {
      float sv = (lane == 0) ? s0 : (lane == 1) ? s1 : (lane == 2) ? s2 : s3;
      s_out[n * 4 + lane] = sv;
    }
    float mx = fmaxf(fmaxf(s0, s1), fmaxf(s2, s3));
    float e0 = __expf(s0 - mx), e1 = __expf(s1 - mx), e2 = __expf(s2 - mx), e3 = __expf(s3 - mx);
    float inv = 1.f / (e0 + e1 + e2 + e3);
    e0 *= inv; e1 *= inv; e2 *= inv; e3 *= inv;
    float x1 = (ze1[n * 64 + lane] - me1) * re1;
    float x2 = (ze2[n * 64 + lane] - me2) * re2;
    float x3 = (ze3[n * 64 + lane] - me3) * re3;
    acc[0] += e0 * x1; acc[1] += e0 * x2; acc[2] += e0 * x3;
    acc[3] += e1 * x1; acc[4] += e1 * x2; acc[5] += e1 * x3;
    acc[6] += e2 * x1; acc[7] += e2 * x2; acc[8] += e2 * x3;
    acc[9] += e3 * x1; acc[10] += e3 * x2; acc[11] += e3 * x3;
  }
#pragma unroll
  for (int u = 0; u < 12; ++u) red[wv][u][lane] = acc[u];
  __syncthreads();
  for (int u = tid; u < 768; u += 256) {
    int f = u & 63, q = u >> 6;
    float v = red[0][q][f] + red[1][q][f] + red[2][q][f] + red[3][q][f];
    int k = q / 3, slot = q - 3 * k;
    atomicAdd(&sx_acc[k * 192 + slot * 64 + f], v);
  }
}

// ---- final (with fused cluster MLP): grid 512 blocks ----
__global__ __launch_bounds__(256) void k_final(
    const float* __restrict__ ze1, const float* __restrict__ ze2, const float* __restrict__ ze3,
    const float* __restrict__ se1, const float* __restrict__ se2, const float* __restrict__ se3,
    const float* __restrict__ ew, const float* __restrict__ ebv,
    const float* __restrict__ l3w, const float* __restrict__ l3b,
    const float* __restrict__ s_out,
    const float* __restrict__ sxacc,
    const float* __restrict__ l1w, const float* __restrict__ l1b,
    const float* __restrict__ l2w, const float* __restrict__ l2b,
    const int* __restrict__ flag, void* __restrict__ out) {
  __shared__ float ewT[192 * 33];          // padded
  __shared__ float l3T[48 * 17];
  __shared__ float ebs[32], l3bs[16];
  __shared__ float xev[4][192];
  __shared__ float xed[4][32];
  __shared__ float tl[4][64];
  __shared__ float sx2l[64];
  int tid = threadIdx.x, lane = tid & 63, wv = tid >> 6;

  for (int i = tid; i < 6144; i += 256) { int cp = i / 192, c = i - cp * 192; ewT[c * 33 + cp] = ew[i]; }
  for (int i = tid; i < 768; i += 256) { int o = i / 48, j = i - o * 48; l3T[j * 17 + o] = l3w[i]; }
  if (tid < 32) ebs[tid] = ebv[tid];
  if (tid < 16) l3bs[tid] = l3b[tid];

  // fused cluster MLP (redundant per block; deterministic)
  {
    int k = tid >> 6, f = tid & 63;
    float v = l1b[f];
    const float4* Ar = (const float4*)(sxacc + k * 192);
    const float4* Wr = (const float4*)(l1w + f * 192);
#pragma unroll 8
    for (int c4 = 0; c4 < 48; ++c4) {
      float4 a = Ar[c4], w = Wr[c4];
      v += a.x * w.x + a.y * w.y + a.z * w.z + a.w * w.w;
    }
    tl[k][f] = fmaxf(v, 0.f);
  }
  __syncthreads();
  if (tid < 64) {
    int kk = tid >> 4, o = tid & 15;
    float u = l2b[o];
#pragma unroll
    for (int j = 0; j < 64; ++j) u += tl[kk][j] * l2w[o * 64 + j];
    sx2l[kk * 16 + o] = u;
  }

  float me1 = se1[lane] * (1.f / NN); float re1 = rsqrtf(se1[64 + lane] * (1.f / NN) - me1 * me1 + 1e-5f);
  float me2 = se2[lane] * (1.f / NN); float re2 = rsqrtf(se2[64 + lane] * (1.f / NN) - me2 * me2 + 1e-5f);
  float me3 = se3[lane] * (1.f / NN); float re3 = rsqrtf(se3[64 + lane] * (1.f / NN) - me3 * me3 + 1e-5f);
  bool bf = (flag[0] == 1);
  __syncthreads();   // staging barrier; body is wave-private

  int h = lane >> 5, L = lane & 31;
  int wave_id = blockIdx.x * 4 + wv;       // 0..2047
  for (int n = wave_id; n < NN; n += 2048) {
    float x1 = (ze1[n * 64 + lane] - me1) * re1;
    float x2 = (ze2[n * 64 + lane] - me2) * re2;
    float x3 = (ze3[n * 64 + lane] - me3) * re3;
    xev[wv][lane] = x1;
    xev[wv][64 + lane] = x2;
    xev[wv][128 + lane] = x3;
    float v = (h == 0) ? ebs[L] : 0.f;
    int cb = h * 96;
#pragma unroll
    for (int c4 = 0; c4 < 24; ++c4) {
      const float4 xv = *(const float4*)&xev[wv][cb + c4 * 4];
      int c0 = cb + c4 * 4;
      v += xv.x * ewT[(c0 + 0) * 33 + L];
      v += xv.y * ewT[(c0 + 1) * 33 + L];
      v += xv.z * ewT[(c0 + 2) * 33 + L];
      v += xv.w * ewT[(c0 + 3) * 33 + L];
    }
    v += __shfl_xor(v, 32);
    if (h == 0) xed[wv][L] = v;
    if (lane < 16) {
      int idx = 0; float best = s_out[n * 4 + 0];
      float c1 = s_out[n * 4 + 1]; if (c1 > best) { best = c1; idx = 1; }
      float c2 = s_out[n * 4 + 2]; if (c2 > best) { best = c2; idx = 2; }
      float c3 = s_out[n * 4 + 3]; if (c3 > best) { best = c3; idx = 3; }
      float racc = l3bs[lane];
#pragma unroll
      for (int j = 0; j < 32; ++j) racc += xed[wv][j] * l3T[j * 17 + lane];
      const float* sxr = sx2l + idx * 16;
#pragma unroll
      for (int j = 0; j < 16; ++j) racc += sxr[j] * l3T[(32 + j) * 17 + lane];
      if (bf) ((__hip_bfloat16*)out)[n * 16 + lane] = __float2bfloat16(racc);
      else    ((float*)out)[n * 16 + lane] = racc;
    }
  }
}

extern "C" void kernel_launch(void* const* d_in, const int* in_sizes, int n_in,
                              void* d_out, int out_size, void* d_ws, size_t ws_size,
                              hipStream_t stream) {
  float* F = (float*)d_ws;
  int* I = (int*)d_ws;

  static const int pcnt[29] = {6400, 4096, 4096, 64, 4096, 4096, 64, 256, 256, 4, 528, 4,
                               4096, 4096, 64, 4096, 4096, 64, 4096, 4096, 64,
                               12288, 64, 1024, 16, 6144, 32, 768, 16};
  int poff[29];
  { int a = 0; for (int i = 0; i < 29; ++i) { poff[i] = a; a += pcnt[i]; } }

  PtrTab tab;
  for (int i = 0; i < 29; ++i) { tab.src[i] = d_in[i]; tab.off[i] = poff[i]; tab.cnt[i] = pcnt[i]; }

  const int* ei = (const int*)d_in[29];
  const int* nt = (const int*)d_in[30];

  int* deg = I + W_DEG;
  int* cur = I + W_CUR;
  int* rowptr = I + W_ROWPTR;
  int* col = I + W_COL;
  int* flag = I + W_FLAG;
  float* st = F + W_STATS;
  float* sxacc = F + W_SXACC;
  float* x0 = F + W_X0;
  float* zp1 = F + W_ZP1; float* zp2 = F + W_ZP2; float* zp3 = F + W_ZP3;
  float* ze1 = F + W_ZE1; float* ze2 = F + W_ZE2; float* ze3 = F + W_ZE3;
  float* sbuf = F + W_S;
  float* P = F + W_PAR;
#define PP(i) (P + poff[i])

  hipMemsetAsync(d_ws, 0, (size_t)W_ZEND * 4, stream);
  k_prelude<<<1154, 256, 0, stream>>>(tab, P, nt, x0, ei, deg, flag);
  k_scan<<<1, 1024, 0, stream>>>(deg, rowptr);
  k_scatter<<<750, 256, 0, stream>>>(ei, rowptr, cur, col);

  // layer 1 (pool & embed share input x0, no input BN)
  k_dual<64, 64, false><<<1024, 256, 0, stream>>>(
      x0, nullptr, PP(1), PP(2), PP(3), zp1, st + 0 * 128,
      x0, nullptr, PP(12), PP(13), PP(14), ze1, st + 3 * 128,
      rowptr, col, 512);
  // layer 2
  k_dual<64, 64, true><<<1024, 256, 0, stream>>>(
      zp1, st + 0 * 128, PP(4), PP(5), PP(6), zp2, st + 1 * 128,
      ze1, st + 3 * 128, PP(15), PP(16), PP(17), ze2, st + 4 * 128,
      rowptr, col, 512);
  // layer 3
  k_dual<4, 64, true><<<1024, 256, 0, stream>>>(
      zp2, st + 1 * 128, PP(7), PP(8), PP(9), zp3, st + 2 * 128,
      ze2, st + 4 * 128, PP(18), PP(19), PP(20), ze3, st + 5 * 128,
      rowptr, col, 512);

  k_pool<<<375, 256, 0, stream>>>(zp1, zp2, zp3, st + 0 * 128, st + 1 * 128, st + 2 * 128,
                                  ze1, ze2, ze3, st + 3 * 128, st + 4 * 128, st + 5 * 128,
                                  PP(10), PP(11), sbuf, sxacc);
  k_final<<<512, 256, 0, stream>>>(ze1, ze2, ze3, st + 3 * 128, st + 4 * 128, st + 5 * 128,
                                   PP(25), PP(26), PP(27), PP(28), sbuf,
                                   sxacc, PP(21), PP(22), PP(23), PP(24), flag, d_out);
}

// Round 8
// 282.241 us; speedup vs baseline: 1.3645x; 1.3645x over previous
//
#include <hip/hip_runtime.h>
#include <hip/hip_bf16.h>

#define NN 6000
#define EE 192000

// ---------------- workspace layout (in 4-byte words) ----------------
#define W_DEG     0
#define W_CUR     6000
#define W_STATS   12000        // 6 slots x 128 (sum[64], sumsq[64])
#define W_SXACC   12768        // 4 x 192
#define W_ZEND    13536
#define W_FLAG    13536
#define W_ROWPTR  13540        // 6001
#define W_COL     19544        // 192000
#define W_X0      211544       // 6000*64
#define W_ZP1     595544
#define W_ZP2     979544
#define W_ZP3     1363544      // 6000*4
#define W_ZE1     1387544
#define W_ZE2     1771544
#define W_ZE3     2155544
#define W_S       2539544      // 6000*4
#define W_SX2     2563544      // 64
#define W_PAR     2563608      // fp32 param region

struct PtrTab {
  const void* src[29];
  int off[29];
  int cnt[29];
};

__device__ __forceinline__ float bf2f(unsigned short h) {
  return __uint_as_float(((unsigned)h) << 16);
}
__device__ __forceinline__ int rfl(int x) { return __builtin_amdgcn_readfirstlane(x); }

// ---- fused prelude: dtype detect (per-block, redundant) + param convert +
// embedding gather (inline dtype) + degree count. 1154 blocks:
// [0,29) convert, [29,404) emb, [404,1154) deg.
__global__ __launch_bounds__(256) void k_prelude(
    PtrTab tab, float* __restrict__ base,
    const int* __restrict__ nt, float* __restrict__ x0,
    const int* __restrict__ ei, int* __restrict__ deg, int* __restrict__ flag) {
  __shared__ int s_ok;
  int tid = threadIdx.x;
  const unsigned short* ep = (const unsigned short*)tab.src[0];
  if (tid == 0) s_ok = 1;
  __syncthreads();
  float v0 = bf2f(ep[tid]), v1 = bf2f(ep[tid + 256]);
  if (!(fabsf(v0) <= 100.f) || !(fabsf(v1) <= 100.f)) atomicAnd(&s_ok, 0);
  __syncthreads();
  bool bf = (s_ok != 0);
  int b = blockIdx.x;
  if (b == 0 && tid == 0) flag[0] = bf ? 1 : 0;

  if (b < 29) {
    const void* s = tab.src[b];
    float* d = base + tab.off[b];
    int n = tab.cnt[b];
    if (bf) {
      const unsigned short* sp = (const unsigned short*)s;
      for (int i = tid; i < n; i += 256) d[i] = bf2f(sp[i]);
    } else {
      const float* sp = (const float*)s;
      for (int i = tid; i < n; i += 256) d[i] = sp[i];
    }
  } else if (b < 404) {
    int t = (b - 29) * 256 + tid;            // 96000 threads
    int i = t >> 4, q = t & 15;
    int row = nt[i];
    if (bf) {
      const unsigned short* sp = (const unsigned short*)tab.src[0] + row * 64 + q * 4;
      float4 o;
      o.x = bf2f(sp[0]); o.y = bf2f(sp[1]); o.z = bf2f(sp[2]); o.w = bf2f(sp[3]);
      *(float4*)&x0[i * 64 + q * 4] = o;
    } else {
      *(float4*)&x0[i * 64 + q * 4] =
          *(const float4*)((const float*)tab.src[0] + row * 64 + q * 4);
    }
  } else {
    int e = (b - 404) * 256 + tid;
    if (e < EE) atomicAdd(&deg[ei[e]], 1);
  }
}

__global__ void k_scan(const int* __restrict__ deg, int* __restrict__ rowptr) {
  __shared__ int part[1024];
  int t = threadIdx.x;
  int base = t * 6;
  int loc[6]; int s = 0;
#pragma unroll
  for (int j = 0; j < 6; ++j) { int i = base + j; int v = (i < NN) ? deg[i] : 0; loc[j] = s; s += v; }
  part[t] = s;
  __syncthreads();
  for (int off = 1; off < 1024; off <<= 1) {
    int v = part[t];
    int add = (t >= off) ? part[t - off] : 0;
    __syncthreads();
    part[t] = v + add;
    __syncthreads();
  }
  int pre = (t == 0) ? 0 : part[t - 1];
#pragma unroll
  for (int j = 0; j < 6; ++j) { int i = base + j; if (i <= NN) rowptr[i] = pre + loc[j]; }
}

__global__ void k_scatter(const int* __restrict__ ei, const int* __restrict__ rowptr,
                          int* __restrict__ cur, int* __restrict__ col) {
  int e = blockIdx.x * 256 + threadIdx.x;
  if (e < EE) {
    int s = ei[e], d = ei[EE + e];
    int pos = atomicAdd(&cur[s], 1);
    col[rowptr[s] + pos] = d;
  }
}

// ---- fused DenseSAGE body: feature-per-lane gather, EXACT round-3 shape.
// lane l == feature l. Per neighbor e: j = v_readlane(colv, e) -> uniform SGPR
// base, wave loads in_z[j*64 + lane] as one coalesced 256B dword load with
// SALU-only addressing. Neighbor sums accumulate in-lane. Weights in LDS
// transposed+padded (conflict-free 2-lanes/bank scalar reads).
// HARD CONSTRAINT (rounds 2/5/7 evidence): body must stay within 64 VGPRs —
// the compiler spills rather than exceed 64, and spill traffic evicts the
// L2 gather set (FETCH 16->117 MB). Do not add live state here.
template <int OUT, bool HS>
__device__ __forceinline__ void sage_body(
    const float* __restrict__ in_z, const float* __restrict__ in_stats,
    const float* __restrict__ wr, const float* __restrict__ wl, const float* __restrict__ bias,
    const int* __restrict__ rowptr, const int* __restrict__ col,
    float* __restrict__ out_z, float* __restrict__ out_stats,
    int vb, int total_waves,
    float* __restrict__ wrT, float* __restrict__ wlT, float* __restrict__ bs,
    float (* __restrict__ vec)[2][64], float (* __restrict__ red)[2][64]) {
  int tid = threadIdx.x, lane = tid & 63, wv = tid >> 6;

  for (int i = tid; i < 64 * OUT; i += 256) {
    int f = i >> 6, k = i & 63;                 // w row-major [OUT][64]: row f, col k
    wrT[k * (OUT + 1) + f] = wr[i];             // transposed + padded: conflict-free
    wlT[k * (OUT + 1) + f] = wl[i];
  }
  if (tid < OUT) bs[tid] = bias[tid];

  float m = 0.f, r = 1.f;
  if (HS) {
    float s = in_stats[lane], q = in_stats[64 + lane];
    m = s * (1.f / NN);
    r = rsqrtf(q * (1.f / NN) - m * m + 1e-5f);
  }
  __syncthreads();   // weights staged; no further barriers until epilogue

  float accs = 0.f, accq = 0.f;
  int ol = lane & (OUT - 1);
  int wave_id = vb * 4 + wv;
  for (int n = wave_id; n < NN; n += total_waves) {
    float x = (in_z[n * 64 + lane] - m) * r;
    int rs = rfl(rowptr[n]), re = rfl(rowptr[n + 1]);
    int cnt = re - rs;
    float sz = 0.f;
    for (int base = rs; base < re; base += 64) {
      int ci = base + lane;
      int colv = col[ci < re ? ci : (re - 1)];   // clamped: lanes >= count hold a valid row
      int full = re - base; if (full > 64) full = 64;  // uniform
      int ng8 = (full + 7) >> 3;
      for (int g = 0; g < ng8; ++g) {
        int e0 = g * 8;
#pragma unroll
        for (int u = 0; u < 8; ++u) {
          int j = __builtin_amdgcn_readlane(colv, e0 + u);   // uniform SGPR
          float v = in_z[j * 64 + lane];                      // coalesced 256B wave load
          sz += (e0 + u < full) ? v : 0.f;                    // uniform cndmask
        }
      }
    }
    float fc = (float)cnt;
    float inv = 1.f / (float)(cnt > 0 ? cnt : 1);
    float a = (sz - fc * m) * r * inv;           // mean of normalized neighbors
    vec[wv][0][lane] = a;
    vec[wv][1][lane] = x;
    // wave-synchronous LDS write->read (in-order DS pipe within a wave)
    float y = bs[ol];
    const float* va = &vec[wv][0][0];
    const float* vx = &vec[wv][1][0];
#pragma unroll
    for (int kk = 0; kk < 16; ++kk) {
      const float4 a4 = *(const float4*)(va + kk * 4);   // broadcast
      const float4 x4 = *(const float4*)(vx + kk * 4);
      int k0 = kk * 4;
      y += a4.x * wrT[(k0 + 0) * (OUT + 1) + ol] + x4.x * wlT[(k0 + 0) * (OUT + 1) + ol];
      y += a4.y * wrT[(k0 + 1) * (OUT + 1) + ol] + x4.y * wlT[(k0 + 1) * (OUT + 1) + ol];
      y += a4.z * wrT[(k0 + 2) * (OUT + 1) + ol] + x4.z * wlT[(k0 + 2) * (OUT + 1) + ol];
      y += a4.w * wrT[(k0 + 3) * (OUT + 1) + ol] + x4.w * wlT[(k0 + 3) * (OUT + 1) + ol];
    }
    float z = fmaxf(y, 0.f);
    if (lane < OUT) {
      out_z[n * OUT + lane] = z;
      accs += z; accq += z * z;
    }
  }
  if (lane < OUT) { red[wv][0][lane] = accs; red[wv][1][lane] = accq; }
  __syncthreads();
  if (tid < OUT) {
    float s = red[0][0][tid] + red[1][0][tid] + red[2][0][tid] + red[3][0][tid];
    float q = red[0][1][tid] + red[1][1][tid] + red[2][1][tid] + red[3][1][tid];
    atomicAdd(&out_stats[tid], s);
    atomicAdd(&out_stats[64 + tid], q);
  }
}

// dual-path sage, XCD-partitioned: blocks land on XCD (blockIdx % 8) round-robin.
// XCDs 0-3 run path A, XCDs 4-7 run path B, so each XCD's 4 MiB L2 only holds
// ONE path's working set (in 1.5 MB + col 0.77 MB) -> gathers hit L2.
template <int OUTA, int OUTB, bool HS>
__global__ __launch_bounds__(256, 4) void k_dual(
    const float* __restrict__ inA, const float* __restrict__ stA,
    const float* __restrict__ wrA, const float* __restrict__ wlA, const float* __restrict__ bA,
    float* __restrict__ outA, float* __restrict__ ostA,
    const float* __restrict__ inB, const float* __restrict__ stB,
    const float* __restrict__ wrB, const float* __restrict__ wlB, const float* __restrict__ bB,
    float* __restrict__ outB, float* __restrict__ ostB,
    const int* __restrict__ rowptr, const int* __restrict__ col, int G) {
  __shared__ float wrT[64 * 65];
  __shared__ float wlT[64 * 65];
  __shared__ float bs[64];
  __shared__ float vec[4][2][64];
  __shared__ float red[4][2][64];
  int bx = (int)blockIdx.x;
  int hi = (bx >> 2) & 1;                 // XCD 0-3 -> path A, XCD 4-7 -> path B
  int vb = (bx >> 3) * 4 + (bx & 3);      // 0..G-1 within the path
  if (hi == 0)
    sage_body<OUTA, HS>(inA, stA, wrA, wlA, bA, rowptr, col, outA, ostA,
                        vb, G * 4, wrT, wlT, bs, vec, red);
  else
    sage_body<OUTB, HS>(inB, stB, wrB, wlB, bB, rowptr, col, outB, ostB,
                        vb, G * 4, wrT, wlT, bs, vec, red);
}

// ---- pool head: grid 375 blocks, 4 nodes per wave ----
__global__ __launch_bounds__(256) void k_pool(
    const float* __restrict__ zp1, const float* __restrict__ zp2, const float* __restrict__ zp3,
    const float* __restrict__ sp1, const float* __restrict__ sp2, const float* __restrict__ sp3,
    const float* __restrict__ ze1, const float* __restrict__ ze2, const float* __restrict__ ze3,
    const float* __restrict__ se1, const float* __restrict__ se2, const float* __restrict__ se3,
    const float* __restrict__ plw, const float* __restrict__ plb,
    float* __restrict__ s_out, float* __restrict__ sx_acc) {
  __shared__ float red[4][12][64];
  int tid = threadIdx.x, lane = tid & 63, wv = tid >> 6;

  float mp1 = sp1[lane] * (1.f / NN); float rp1 = rsqrtf(sp1[64 + lane] * (1.f / NN) - mp1 * mp1 + 1e-5f);
  float mp2 = sp2[lane] * (1.f / NN); float rp2 = rsqrtf(sp2[64 + lane] * (1.f / NN) - mp2 * mp2 + 1e-5f);
  float mp3 = 0.f, rp3 = 1.f;
  if (lane < 4) { mp3 = sp3[lane] * (1.f / NN); rp3 = rsqrtf(sp3[64 + lane] * (1.f / NN) - mp3 * mp3 + 1e-5f); }
  float me1 = se1[lane] * (1.f / NN); float re1 = rsqrtf(se1[64 + lane] * (1.f / NN) - me1 * me1 + 1e-5f);
  float me2 = se2[lane] * (1.f / NN); float re2 = rsqrtf(se2[64 + lane] * (1.f / NN) - me2 * me2 + 1e-5f);
  float me3 = se3[lane] * (1.f / NN); float re3 = rsqrtf(se3[64 + lane] * (1.f / NN) - me3 * me3 + 1e-5f);

  float w0a = plw[0 * 132 + lane], w0b = plw[0 * 132 + 64 + lane], w0c = (lane < 4) ? plw[0 * 132 + 128 + lane] : 0.f;
  float w1a = plw[1 * 132 + lane], w1b = plw[1 * 132 + 64 + lane], w1c = (lane < 4) ? plw[1 * 132 + 128 + lane] : 0.f;
  float w2a = plw[2 * 132 + lane], w2b = plw[2 * 132 + 64 + lane], w2c = (lane < 4) ? plw[2 * 132 + 128 + lane] : 0.f;
  float w3a = plw[3 * 132 + lane], w3b = plw[3 * 132 + 64 + lane], w3c = (lane < 4) ? plw[3 * 132 + 128 + lane] : 0.f;
  float pb0 = plb[0], pb1v = plb[1], pb2v = plb[2], pb3v = plb[3];

  float acc[12];
#pragma unroll
  for (int u = 0; u < 12; ++u) acc[u] = 0.f;

  int wave_id = blockIdx.x * 4 + wv;       // 0..1499
  for (int n = wave_id; n < NN; n += 1500) {
    float a = (zp1[n * 64 + lane] - mp1) * rp1;
    float b = (zp2[n * 64 + lane] - mp2) * rp2;
    float c = (lane < 4) ? ((zp3[n * 4 + lane] - mp3) * rp3) : 0.f;
    float p0 = a * w0a + b * w0b + c * w0c;
    float p1 = a * w1a + b * w1b + c * w1c;
    float p2 = a * w2a + b * w2b + c * w2c;
    float p3 = a * w3a + b * w3b + c * w3c;
#pragma unroll
    for (int off = 1; off < 64; off <<= 1) {
      p0 += __shfl_xor(p0, off);
      p1 += __shfl_xor(p1, off);
      p2 += __shfl_xor(p2, off);
      p3 += __shfl_xor(p3, off);
    }
    float s0 = fmaxf(p0 + pb0, 0.f), s1 = fmaxf(p1 + pb1v, 0.f);
    float s2 = fmaxf(p2 + pb2v, 0.f), s3 = fmaxf(p3 + pb3v, 0.f);
    if (lane < 4) {
      float sv = (lane == 0) ? s0 : (lane == 1) ? s1 : (lane == 2) ? s2 : s3;
      s_out[n * 4 + lane] = sv;
    }
    float mx = fmaxf(fmaxf(s0, s1), fmaxf(s2, s3));
    float e0 = __expf(s0 - mx), e1 = __expf(s1 - mx), e2 = __expf(s2 - mx), e3 = __expf(s3 - mx);
    float inv = 1.f / (e0 + e1 + e2 + e3);
    e0 *= inv; e1 *= inv; e2 *= inv; e3 *= inv;
    float x1 = (ze1[n * 64 + lane] - me1) * re1;
    float x2 = (ze2[n * 64 + lane] - me2) * re2;
    float x3 = (ze3[n * 64 + lane] - me3) * re3;
    acc[0] += e0 * x1; acc[1] += e0 * x2; acc[2] += e0 * x3;
    acc[3] += e1 * x1; acc[4] += e1 * x2; acc[5] += e1 * x3;
    acc[6] += e2 * x1; acc[7] += e2 * x2; acc[8] += e2 * x3;
    acc[9] += e3 * x1; acc[10] += e3 * x2; acc[11] += e3 * x3;
  }
#pragma unroll
  for (int u = 0; u < 12; ++u) red[wv][u][lane] = acc[u];
  __syncthreads();
  for (int u = tid; u < 768; u += 256) {
    int f = u & 63, q = u >> 6;
    float v = red[0][q][f] + red[1][q][f] + red[2][q][f] + red[3][q][f];
    int k = q / 3, slot = q - 3 * k;
    atomicAdd(&sx_acc[k * 192 + slot * 64 + f], v);
  }
}

// ---- final (with fused cluster MLP): grid 512 blocks ----
__global__ __launch_bounds__(256) void k_final(
    const float* __restrict__ ze1, const float* __restrict__ ze2, const float* __restrict__ ze3,
    const float* __restrict__ se1, const float* __restrict__ se2, const float* __restrict__ se3,
    const float* __restrict__ ew, const float* __restrict__ ebv,
    const float* __restrict__ l3w, const float* __restrict__ l3b,
    const float* __restrict__ s_out,
    const float* __restrict__ sxacc,
    const float* __restrict__ l1w, const float* __restrict__ l1b,
    const float* __restrict__ l2w, const float* __restrict__ l2b,
    const int* __restrict__ flag, void* __restrict__ out) {
  __shared__ float ewT[192 * 33];          // padded
  __shared__ float l3T[48 * 17];
  __shared__ float ebs[32], l3bs[16];
  __shared__ float xev[4][192];
  __shared__ float xed[4][32];
  __shared__ float tl[4][64];
  __shared__ float sx2l[64];
  int tid = threadIdx.x, lane = tid & 63, wv = tid >> 6;

  for (int i = tid; i < 6144; i += 256) { int cp = i / 192, c = i - cp * 192; ewT[c * 33 + cp] = ew[i]; }
  for (int i = tid; i < 768; i += 256) { int o = i / 48, j = i - o * 48; l3T[j * 17 + o] = l3w[i]; }
  if (tid < 32) ebs[tid] = ebv[tid];
  if (tid < 16) l3bs[tid] = l3b[tid];

  // fused cluster MLP (redundant per block; deterministic)
  {
    int k = tid >> 6, f = tid & 63;
    float v = l1b[f];
    const float4* Ar = (const float4*)(sxacc + k * 192);
    const float4* Wr = (const float4*)(l1w + f * 192);
#pragma unroll 8
    for (int c4 = 0; c4 < 48; ++c4) {
      float4 a = Ar[c4], w = Wr[c4];
      v += a.x * w.x + a.y * w.y + a.z * w.z + a.w * w.w;
    }
    tl[k][f] = fmaxf(v, 0.f);
  }
  __syncthreads();
  if (tid < 64) {
    int kk = tid >> 4, o = tid & 15;
    float u = l2b[o];
#pragma unroll
    for (int j = 0; j < 64; ++j) u += tl[kk][j] * l2w[o * 64 + j];
    sx2l[kk * 16 + o] = u;
  }

  float me1 = se1[lane] * (1.f / NN); float re1 = rsqrtf(se1[64 + lane] * (1.f / NN) - me1 * me1 + 1e-5f);
  float me2 = se2[lane] * (1.f / NN); float re2 = rsqrtf(se2[64 + lane] * (1.f / NN) - me2 * me2 + 1e-5f);
  float me3 = se3[lane] * (1.f / NN); float re3 = rsqrtf(se3[64 + lane] * (1.f / NN) - me3 * me3 + 1e-5f);
  bool bf = (flag[0] == 1);
  __syncthreads();   // staging barrier; body is wave-private

  int h = lane >> 5, L = lane & 31;
  int wave_id = blockIdx.x * 4 + wv;       // 0..2047
  for (int n = wave_id; n < NN; n += 2048) {
    float x1 = (ze1[n * 64 + lane] - me1) * re1;
    float x2 = (ze2[n * 64 + lane] - me2) * re2;
    float x3 = (ze3[n * 64 + lane] - me3) * re3;
    xev[wv][lane] = x1;
    xev[wv][64 + lane] = x2;
    xev[wv][128 + lane] = x3;
    float v = (h == 0) ? ebs[L] : 0.f;
    int cb = h * 96;
#pragma unroll
    for (int c4 = 0; c4 < 24; ++c4) {
      const float4 xv = *(const float4*)&xev[wv][cb + c4 * 4];
      int c0 = cb + c4 * 4;
      v += xv.x * ewT[(c0 + 0) * 33 + L];
      v += xv.y * ewT[(c0 + 1) * 33 + L];
      v += xv.z * ewT[(c0 + 2) * 33 + L];
      v += xv.w * ewT[(c0 + 3) * 33 + L];
    }
    v += __shfl_xor(v, 32);
    if (h == 0) xed[wv][L] = v;
    if (lane < 16) {
      int idx = 0; float best = s_out[n * 4 + 0];
      float c1 = s_out[n * 4 + 1]; if (c1 > best) { best = c1; idx = 1; }
      float c2 = s_out[n * 4 + 2]; if (c2 > best) { best = c2; idx = 2; }
      float c3 = s_out[n * 4 + 3]; if (c3 > best) { best = c3; idx = 3; }
      float racc = l3bs[lane];
#pragma unroll
      for (int j = 0; j < 32; ++j) racc += xed[wv][j] * l3T[j * 17 + lane];
      const float* sxr = sx2l + idx * 16;
#pragma unroll
      for (int j = 0; j < 16; ++j) racc += sxr[j] * l3T[(32 + j) * 17 + lane];
      if (bf) ((__hip_bfloat16*)out)[n * 16 + lane] = __float2bfloat16(racc);
      else    ((float*)out)[n * 16 + lane] = racc;
    }
  }
}

extern "C" void kernel_launch(void* const* d_in, const int* in_sizes, int n_in,
                              void* d_out, int out_size, void* d_ws, size_t ws_size,
                              hipStream_t stream) {
  float* F = (float*)d_ws;
  int* I = (int*)d_ws;

  static const int pcnt[29] = {6400, 4096, 4096, 64, 4096, 4096, 64, 256, 256, 4, 528, 4,
                               4096, 4096, 64, 4096, 4096, 64, 4096, 4096, 64,
                               12288, 64, 1024, 16, 6144, 32, 768, 16};
  int poff[29];
  { int a = 0; for (int i = 0; i < 29; ++i) { poff[i] = a; a += pcnt[i]; } }

  PtrTab tab;
  for (int i = 0; i < 29; ++i) { tab.src[i] = d_in[i]; tab.off[i] = poff[i]; tab.cnt[i] = pcnt[i]; }

  const int* ei = (const int*)d_in[29];
  const int* nt = (const int*)d_in[30];

  int* deg = I + W_DEG;
  int* cur = I + W_CUR;
  int* rowptr = I + W_ROWPTR;
  int* col = I + W_COL;
  int* flag = I + W_FLAG;
  float* st = F + W_STATS;
  float* sxacc = F + W_SXACC;
  float* x0 = F + W_X0;
  float* zp1 = F + W_ZP1; float* zp2 = F + W_ZP2; float* zp3 = F + W_ZP3;
  float* ze1 = F + W_ZE1; float* ze2 = F + W_ZE2; float* ze3 = F + W_ZE3;
  float* sbuf = F + W_S;
  float* P = F + W_PAR;
#define PP(i) (P + poff[i])

  hipMemsetAsync(d_ws, 0, (size_t)W_ZEND * 4, stream);
  k_prelude<<<1154, 256, 0, stream>>>(tab, P, nt, x0, ei, deg, flag);
  k_scan<<<1, 1024, 0, stream>>>(deg, rowptr);
  k_scatter<<<750, 256, 0, stream>>>(ei, rowptr, cur, col);

  // layer 1 (pool & embed share input x0, no input BN)
  k_dual<64, 64, false><<<1024, 256, 0, stream>>>(
      x0, nullptr, PP(1), PP(2), PP(3), zp1, st + 0 * 128,
      x0, nullptr, PP(12), PP(13), PP(14), ze1, st + 3 * 128,
      rowptr, col, 512);
  // layer 2
  k_dual<64, 64, true><<<1024, 256, 0, stream>>>(
      zp1, st + 0 * 128, PP(4), PP(5), PP(6), zp2, st + 1 * 128,
      ze1, st + 3 * 128, PP(15), PP(16), PP(17), ze2, st + 4 * 128,
      rowptr, col, 512);
  // layer 3
  k_dual<4, 64, true><<<1024, 256, 0, stream>>>(
      zp2, st + 1 * 128, PP(7), PP(8), PP(9), zp3, st + 2 * 128,
      ze2, st + 4 * 128, PP(18), PP(19), PP(20), ze3, st + 5 * 128,
      rowptr, col, 512);

  k_pool<<<375, 256, 0, stream>>>(zp1, zp2, zp3, st + 0 * 128, st + 1 * 128, st + 2 * 128,
                                  ze1, ze2, ze3, st + 3 * 128, st + 4 * 128, st + 5 * 128,
                                  PP(10), PP(11), sbuf, sxacc);
  k_final<<<512, 256, 0, stream>>>(ze1, ze2, ze3, st + 3 * 128, st + 4 * 128, st + 5 * 128,
                                   PP(25), PP(26), PP(27), PP(28), sbuf,
                                   sxacc, PP(21), PP(22), PP(23), PP(24), flag, d_out);
}

// Round 10
// 275.585 us; speedup vs baseline: 1.3975x; 1.0242x over previous
//
#include <hip/hip_runtime.h>
#include <hip/hip_bf16.h>

#define NN 6000
#define EE 192000

// ---------------- workspace layout (in 4-byte words) ----------------
#define W_DEG     0
#define W_CUR     6000
#define W_STATS   12000        // 6 slots x 128 (sum[64], sumsq[64])
#define W_SXACC   12768        // 4 x 192
#define W_ZEND    13536
#define W_FLAG    13536
#define W_ROWPTR  13540        // 6001
#define W_COL     19544        // 192000
#define W_X0      211544       // 6000*64
#define W_ZP1     595544
#define W_ZP2     979544
#define W_ZP3     1363544      // 6000*4
#define W_ZE1     1387544
#define W_ZE2     1771544
#define W_ZE3     2155544
#define W_S       2539544      // 6000*4
#define W_SX2     2563544      // 64
#define W_PAR     2563608      // fp32 param region

struct PtrTab {
  const void* src[29];
  int off[29];
  int cnt[29];
};

__device__ __forceinline__ float bf2f(unsigned short h) {
  return __uint_as_float(((unsigned)h) << 16);
}
__device__ __forceinline__ int rfl(int x) { return __builtin_amdgcn_readfirstlane(x); }

// ---- fused prelude: dtype detect (per-block, redundant) + param convert +
// embedding gather (inline dtype) + degree count. 1154 blocks:
// [0,29) convert, [29,404) emb, [404,1154) deg.
__global__ __launch_bounds__(256) void k_prelude(
    PtrTab tab, float* __restrict__ base,
    const int* __restrict__ nt, float* __restrict__ x0,
    const int* __restrict__ ei, int* __restrict__ deg, int* __restrict__ flag) {
  __shared__ int s_ok;
  int tid = threadIdx.x;
  const unsigned short* ep = (const unsigned short*)tab.src[0];
  if (tid == 0) s_ok = 1;
  __syncthreads();
  float v0 = bf2f(ep[tid]), v1 = bf2f(ep[tid + 256]);
  if (!(fabsf(v0) <= 100.f) || !(fabsf(v1) <= 100.f)) atomicAnd(&s_ok, 0);
  __syncthreads();
  bool bf = (s_ok != 0);
  int b = blockIdx.x;
  if (b == 0 && tid == 0) flag[0] = bf ? 1 : 0;

  if (b < 29) {
    const void* s = tab.src[b];
    float* d = base + tab.off[b];
    int n = tab.cnt[b];
    if (bf) {
      const unsigned short* sp = (const unsigned short*)s;
      for (int i = tid; i < n; i += 256) d[i] = bf2f(sp[i]);
    } else {
      const float* sp = (const float*)s;
      for (int i = tid; i < n; i += 256) d[i] = sp[i];
    }
  } else if (b < 404) {
    int t = (b - 29) * 256 + tid;            // 96000 threads
    int i = t >> 4, q = t & 15;
    int row = nt[i];
    if (bf) {
      const unsigned short* sp = (const unsigned short*)tab.src[0] + row * 64 + q * 4;
      float4 o;
      o.x = bf2f(sp[0]); o.y = bf2f(sp[1]); o.z = bf2f(sp[2]); o.w = bf2f(sp[3]);
      *(float4*)&x0[i * 64 + q * 4] = o;
    } else {
      *(float4*)&x0[i * 64 + q * 4] =
          *(const float4*)((const float*)tab.src[0] + row * 64 + q * 4);
    }
  } else {
    int e = (b - 404) * 256 + tid;
    if (e < EE) atomicAdd(&deg[ei[e]], 1);
  }
}

__global__ void k_scan(const int* __restrict__ deg, int* __restrict__ rowptr) {
  __shared__ int part[1024];
  int t = threadIdx.x;
  int base = t * 6;
  int loc[6]; int s = 0;
#pragma unroll
  for (int j = 0; j < 6; ++j) { int i = base + j; int v = (i < NN) ? deg[i] : 0; loc[j] = s; s += v; }
  part[t] = s;
  __syncthreads();
  for (int off = 1; off < 1024; off <<= 1) {
    int v = part[t];
    int add = (t >= off) ? part[t - off] : 0;
    __syncthreads();
    part[t] = v + add;
    __syncthreads();
  }
  int pre = (t == 0) ? 0 : part[t - 1];
#pragma unroll
  for (int j = 0; j < 6; ++j) { int i = base + j; if (i <= NN) rowptr[i] = pre + loc[j]; }
}

__global__ void k_scatter(const int* __restrict__ ei, const int* __restrict__ rowptr,
                          int* __restrict__ cur, int* __restrict__ col) {
  int e = blockIdx.x * 256 + threadIdx.x;
  if (e < EE) {
    int s = ei[e], d = ei[EE + e];
    int pos = atomicAdd(&cur[s], 1);
    col[rowptr[s] + pos] = d;
  }
}

// ---- fused DenseSAGE body: feature-per-lane gather + 4-way split chains.
// lane l == feature l; per neighbor e: j = v_readlane(colv, e) -> uniform SGPR
// base, coalesced 256B wave load. Weights transposed+padded in LDS.
// k_dual declares amdgpu_waves_per_eu(3,4): raises the VGPR budget from 64
// (backend's 8-wave heuristic) to 128 — LDS already caps occupancy at
// 4 waves/EU, so this is free. That headroom lets the 4-way split accumulator
// chains (gather szA..D, MAC y0..3) fit in registers instead of spilling
// (round-7 failure mode).
template <int OUT, bool HS>
__device__ __forceinline__ void sage_body(
    const float* __restrict__ in_z, const float* __restrict__ in_stats,
    const float* __restrict__ wr, const float* __restrict__ wl, const float* __restrict__ bias,
    const int* __restrict__ rowptr, const int* __restrict__ col,
    float* __restrict__ out_z, float* __restrict__ out_stats,
    int vb, int total_waves,
    float* __restrict__ wrT, float* __restrict__ wlT, float* __restrict__ bs,
    float (* __restrict__ vec)[2][64], float (* __restrict__ red)[2][64]) {
  int tid = threadIdx.x, lane = tid & 63, wv = tid >> 6;

  for (int i = tid; i < 64 * OUT; i += 256) {
    int f = i >> 6, k = i & 63;                 // w row-major [OUT][64]: row f, col k
    wrT[k * (OUT + 1) + f] = wr[i];             // transposed + padded: conflict-free
    wlT[k * (OUT + 1) + f] = wl[i];
  }
  if (tid < OUT) bs[tid] = bias[tid];

  float m = 0.f, r = 1.f;
  if (HS) {
    float s = in_stats[lane], q = in_stats[64 + lane];
    m = s * (1.f / NN);
    r = rsqrtf(q * (1.f / NN) - m * m + 1e-5f);
  }
  __syncthreads();   // weights staged; no further barriers until epilogue

  float accs = 0.f, accq = 0.f;
  int ol = lane & (OUT - 1);
  int wave_id = vb * 4 + wv;
  for (int n = wave_id; n < NN; n += total_waves) {
    float x = (in_z[n * 64 + lane] - m) * r;
    int rs = rfl(rowptr[n]), re = rfl(rowptr[n + 1]);
    int cnt = re - rs;
    float szA = 0.f, szB = 0.f, szC = 0.f, szD = 0.f;   // 4-way split reduce chain
    for (int base = rs; base < re; base += 64) {
      int ci = base + lane;
      int colv = col[ci < re ? ci : (re - 1)];   // clamped: lanes >= count hold a valid row
      int full = re - base; if (full > 64) full = 64;  // uniform
      int ng8 = (full + 7) >> 3;
      for (int g = 0; g < ng8; ++g) {
        int e0 = g * 8;
#pragma unroll
        for (int u = 0; u < 8; ++u) {
          int j = __builtin_amdgcn_readlane(colv, e0 + u);   // uniform SGPR
          float v = in_z[j * 64 + lane];                      // coalesced 256B wave load
          float vv = (e0 + u < full) ? v : 0.f;               // uniform cndmask
          if ((u & 3) == 0) szA += vv;
          else if ((u & 3) == 1) szB += vv;
          else if ((u & 3) == 2) szC += vv;
          else szD += vv;
        }
      }
    }
    float sz = (szA + szB) + (szC + szD);
    float fc = (float)cnt;
    float inv = 1.f / (float)(cnt > 0 ? cnt : 1);
    float a = (sz - fc * m) * r * inv;           // mean of normalized neighbors
    vec[wv][0][lane] = a;
    vec[wv][1][lane] = x;
    // wave-synchronous LDS write->read (in-order DS pipe within a wave)
    float y0 = bs[ol], y1 = 0.f, y2 = 0.f, y3 = 0.f;   // 4-way split MAC chain
    const float* va = &vec[wv][0][0];
    const float* vx = &vec[wv][1][0];
#pragma unroll
    for (int kk = 0; kk < 16; ++kk) {
      const float4 a4 = *(const float4*)(va + kk * 4);   // broadcast
      const float4 x4 = *(const float4*)(vx + kk * 4);
      int k0 = kk * 4;
      y0 += a4.x * wrT[(k0 + 0) * (OUT + 1) + ol] + x4.x * wlT[(k0 + 0) * (OUT + 1) + ol];
      y1 += a4.y * wrT[(k0 + 1) * (OUT + 1) + ol] + x4.y * wlT[(k0 + 1) * (OUT + 1) + ol];
      y2 += a4.z * wrT[(k0 + 2) * (OUT + 1) + ol] + x4.z * wlT[(k0 + 2) * (OUT + 1) + ol];
      y3 += a4.w * wrT[(k0 + 3) * (OUT + 1) + ol] + x4.w * wlT[(k0 + 3) * (OUT + 1) + ol];
    }
    float y = (y0 + y1) + (y2 + y3);
    float z = fmaxf(y, 0.f);
    if (lane < OUT) {
      out_z[n * OUT + lane] = z;
      accs += z; accq += z * z;
    }
  }
  if (lane < OUT) { red[wv][0][lane] = accs; red[wv][1][lane] = accq; }
  __syncthreads();
  if (tid < OUT) {
    float s = red[0][0][tid] + red[1][0][tid] + red[2][0][tid] + red[3][0][tid];
    float q = red[0][1][tid] + red[1][1][tid] + red[2][1][tid] + red[3][1][tid];
    atomicAdd(&out_stats[tid], s);
    atomicAdd(&out_stats[64 + tid], q);
  }
}

// dual-path sage, XCD-partitioned: blocks land on XCD (blockIdx % 8) round-robin.
// XCDs 0-3 run path A, XCDs 4-7 run path B, so each XCD's 4 MiB L2 only holds
// ONE path's working set (in 1.5 MB + col 0.77 MB) -> gathers hit L2.
// amdgpu_waves_per_eu(3,4): LDS (37.9KB) caps us at 4 blocks/CU = 4 waves/EU
// anyway, so telling the allocator max=4 unlocks a 128-VGPR budget for free.
template <int OUTA, int OUTB, bool HS>
__global__ __launch_bounds__(256)
__attribute__((amdgpu_waves_per_eu(3, 4))) void k_dual(
    const float* __restrict__ inA, const float* __restrict__ stA,
    const float* __restrict__ wrA, const float* __restrict__ wlA, const float* __restrict__ bA,
    float* __restrict__ outA, float* __restrict__ ostA,
    const float* __restrict__ inB, const float* __restrict__ stB,
    const float* __restrict__ wrB, const float* __restrict__ wlB, const float* __restrict__ bB,
    float* __restrict__ outB, float* __restrict__ ostB,
    const int* __restrict__ rowptr, const int* __restrict__ col, int G) {
  __shared__ float wrT[64 * 65];
  __shared__ float wlT[64 * 65];
  __shared__ float bs[64];
  __shared__ float vec[4][2][64];
  __shared__ float red[4][2][64];
  int bx = (int)blockIdx.x;
  int hi = (bx >> 2) & 1;                 // XCD 0-3 -> path A, XCD 4-7 -> path B
  int vb = (bx >> 3) * 4 + (bx & 3);      // 0..G-1 within the path
  if (hi == 0)
    sage_body<OUTA, HS>(inA, stA, wrA, wlA, bA, rowptr, col, outA, ostA,
                        vb, G * 4, wrT, wlT, bs, vec, red);
  else
    sage_body<OUTB, HS>(inB, stB, wrB, wlB, bB, rowptr, col, outB, ostB,
                        vb, G * 4, wrT, wlT, bs, vec, red);
}

// ---- pool head: grid 375 blocks, 4 nodes per wave ----
__global__ __launch_bounds__(256) void k_pool(
    const float* __restrict__ zp1, const float* __restrict__ zp2, const float* __restrict__ zp3,
    const float* __restrict__ sp1, const float* __restrict__ sp2, const float* __restrict__ sp3,
    const float* __restrict__ ze1, const float* __restrict__ ze2, const float* __restrict__ ze3,
    const float* __restrict__ se1, const float* __restrict__ se2, const float* __restrict__ se3,
    const float* __restrict__ plw, const float* __restrict__ plb,
    float* __restrict__ s_out, float* __restrict__ sx_acc) {
  __shared__ float red[4][12][64];
  int tid = threadIdx.x, lane = tid & 63, wv = tid >> 6;

  float mp1 = sp1[lane] * (1.f / NN); float rp1 = rsqrtf(sp1[64 + lane] * (1.f / NN) - mp1 * mp1 + 1e-5f);
  float mp2 = sp2[lane] * (1.f / NN); float rp2 = rsqrtf(sp2[64 + lane] * (1.f / NN) - mp2 * mp2 + 1e-5f);
  float mp3 = 0.f, rp3 = 1.f;
  if (lane < 4) { mp3 = sp3[lane] * (1.f / NN); rp3 = rsqrtf(sp3[64 + lane] * (1.f / NN) - mp3 * mp3 + 1e-5f); }
  float me1 = se1[lane] * (1.f / NN); float re1 = rsqrtf(se1[64 + lane] * (1.f / NN) - me1 * me1 + 1e-5f);
  float me2 = se2[lane] * (1.f / NN); float re2 = rsqrtf(se2[64 + lane] * (1.f / NN) - me2 * me2 + 1e-5f);
  float me3 = se3[lane] * (1.f / NN); float re3 = rsqrtf(se3[64 + lane] * (1.f / NN) - me3 * me3 + 1e-5f);

  float w0a = plw[0 * 132 + lane], w0b = plw[0 * 132 + 64 + lane], w0c = (lane < 4) ? plw[0 * 132 + 128 + lane] : 0.f;
  float w1a = plw[1 * 132 + lane], w1b = plw[1 * 132 + 64 + lane], w1c = (lane < 4) ? plw[1 * 132 + 128 + lane] : 0.f;
  float w2a = plw[2 * 132 + lane], w2b = plw[2 * 132 + 64 + lane], w2c = (lane < 4) ? plw[2 * 132 + 128 + lane] : 0.f;
  float w3a = plw[3 * 132 + lane], w3b = plw[3 * 132 + 64 + lane], w3c = (lane < 4) ? plw[3 * 132 + 128 + lane] : 0.f;
  float pb0 = plb[0], pb1v = plb[1], pb2v = plb[2], pb3v = plb[3];

  float acc[12];
#pragma unroll
  for (int u = 0; u < 12; ++u) acc[u] = 0.f;

  int wave_id = blockIdx.x * 4 + wv;       // 0..1499
  for (int n = wave_id; n < NN; n += 1500) {
    float a = (zp1[n * 64 + lane] - mp1) * rp1;
    float b = (zp2[n * 64 + lane] - mp2) * rp2;
    float c = (lane < 4) ? ((zp3[n * 4 + lane] - mp3) * rp3) : 0.f;
    float p0 = a * w0a + b * w0b + c * w0c;
    float p1 = a * w1a + b * w1b + c * w1c;
    float p2 = a * w2a + b * w2b + c * w2c;
    float p3 = a * w3a + b * w3b + c * w3c;
#pragma unroll
    for (int off = 1; off < 64; off <<= 1) {
      p0 += __shfl_xor(p0, off);
      p1 += __shfl_xor(p1, off);
      p2 += __shfl_xor(p2, off);
      p3 += __shfl_xor(p3, off);
    }
    float s0 = fmaxf(p0 + pb0, 0.f), s1 = fmaxf(p1 + pb1v, 0.f);
    float s2 = fmaxf(p2 + pb2v, 0.f), s3 = fmaxf(p3 + pb3v, 0.f);
    if (lane < 4) {
      float sv = (lane == 0) ? s0 : (lane == 1) ? s1 : (lane == 2) ? s2 : s3;
      s_out[n * 4 + lane] = sv;
    }
    float mx = fmaxf(fmaxf(s0, s1), fmaxf(s2, s3));
    float e0 = __expf(s0 - mx), e1 = __expf(s1 - mx), e2 = __expf(s2 - mx), e3 = __expf(s3 - mx);
    float inv = 1.f / (e0 + e1 + e2 + e3);
    e0 *= inv; e1 *= inv; e2 *= inv; e3 *= inv;
    float x1 = (ze1[n * 64 + lane] - me1) * re1;
    float x2 = (ze2[n * 64 + lane] - me2) * re2;
    float x3 = (ze3[n * 64 + lane] - me3) * re3;
    acc[0] += e0 * x1; acc[1] += e0 * x2; acc[2] += e0 * x3;
    acc[3] += e1 * x1; acc[4] += e1 * x2; acc[5] += e1 * x3;
    acc[6] += e2 * x1; acc[7] += e2 * x2; acc[8] += e2 * x3;
    acc[9] += e3 * x1; acc[10] += e3 * x2; acc[11] += e3 * x3;
  }
#pragma unroll
  for (int u = 0; u < 12; ++u) red[wv][u][lane] = acc[u];
  __syncthreads();
  for (int u = tid; u < 768; u += 256) {
    int f = u & 63, q = u >> 6;
    float v = red[0][q][f] + red[1][q][f] + red[2][q][f] + red[3][q][f];
    int k = q / 3, slot = q - 3 * k;
    atomicAdd(&sx_acc[k * 192 + slot * 64 + f], v);
  }
}

// ---- final (with fused cluster MLP): grid 512 blocks ----
__global__ __launch_bounds__(256) void k_final(
    const float* __restrict__ ze1, const float* __restrict__ ze2, const float* __restrict__ ze3,
    const float* __restrict__ se1, const float* __restrict__ se2, const float* __restrict__ se3,
    const float* __restrict__ ew, const float* __restrict__ ebv,
    const float* __restrict__ l3w, const float* __restrict__ l3b,
    const float* __restrict__ s_out,
    const float* __restrict__ sxacc,
    const float* __restrict__ l1w, const float* __restrict__ l1b,
    const float* __restrict__ l2w, const float* __restrict__ l2b,
    const int* __restrict__ flag, void* __restrict__ out) {
  __shared__ float ewT[192 * 33];          // padded
  __shared__ float l3T[48 * 17];
  __shared__ float ebs[32], l3bs[16];
  __shared__ float xev[4][192];
  __shared__ float xed[4][32];
  __shared__ float tl[4][64];
  __shared__ float sx2l[64];
  int tid = threadIdx.x, lane = tid & 63, wv = tid >> 6;

  for (int i = tid; i < 6144; i += 256) { int cp = i / 192, c = i - cp * 192; ewT[c * 33 + cp] = ew[i]; }
  for (int i = tid; i < 768; i += 256) { int o = i / 48, j = i - o * 48; l3T[j * 17 + o] = l3w[i]; }
  if (tid < 32) ebs[tid] = ebv[tid];
  if (tid < 16) l3bs[tid] = l3b[tid];

  // fused cluster MLP (redundant per block; deterministic)
  {
    int k = tid >> 6, f = tid & 63;
    float v = l1b[f];
    const float4* Ar = (const float4*)(sxacc + k * 192);
    const float4* Wr = (const float4*)(l1w + f * 192);
#pragma unroll 8
    for (int c4 = 0; c4 < 48; ++c4) {
      float4 a = Ar[c4], w = Wr[c4];
      v += a.x * w.x + a.y * w.y + a.z * w.z + a.w * w.w;
    }
    tl[k][f] = fmaxf(v, 0.f);
  }
  __syncthreads();
  if (tid < 64) {
    int kk = tid >> 4, o = tid & 15;
    float u = l2b[o];
#pragma unroll
    for (int j = 0; j < 64; ++j) u += tl[kk][j] * l2w[o * 64 + j];
    sx2l[kk * 16 + o] = u;
  }

  float me1 = se1[lane] * (1.f / NN); float re1 = rsqrtf(se1[64 + lane] * (1.f / NN) - me1 * me1 + 1e-5f);
  float me2 = se2[lane] * (1.f / NN); float re2 = rsqrtf(se2[64 + lane] * (1.f / NN) - me2 * me2 + 1e-5f);
  float me3 = se3[lane] * (1.f / NN); float re3 = rsqrtf(se3[64 + lane] * (1.f / NN) - me3 * me3 + 1e-5f);
  bool bf = (flag[0] == 1);
  __syncthreads();   // staging barrier; body is wave-private

  int h = lane >> 5, L = lane & 31;
  int wave_id = blockIdx.x * 4 + wv;       // 0..2047
  for (int n = wave_id; n < NN; n += 2048) {
    float x1 = (ze1[n * 64 + lane] - me1) * re1;
    float x2 = (ze2[n * 64 + lane] - me2) * re2;
    float x3 = (ze3[n * 64 + lane] - me3) * re3;
    xev[wv][lane] = x1;
    xev[wv][64 + lane] = x2;
    xev[wv][128 + lane] = x3;
    float v = (h == 0) ? ebs[L] : 0.f;
    int cb = h * 96;
#pragma unroll
    for (int c4 = 0; c4 < 24; ++c4) {
      const float4 xv = *(const float4*)&xev[wv][cb + c4 * 4];
      int c0 = cb + c4 * 4;
      v += xv.x * ewT[(c0 + 0) * 33 + L];
      v += xv.y * ewT[(c0 + 1) * 33 + L];
      v += xv.z * ewT[(c0 + 2) * 33 + L];
      v += xv.w * ewT[(c0 + 3) * 33 + L];
    }
    v += __shfl_xor(v, 32);
    if (h == 0) xed[wv][L] = v;
    if (lane < 16) {
      int idx = 0; float best = s_out[n * 4 + 0];
      float c1 = s_out[n * 4 + 1]; if (c1 > best) { best = c1; idx = 1; }
      float c2 = s_out[n * 4 + 2]; if (c2 > best) { best = c2; idx = 2; }
      float c3 = s_out[n * 4 + 3]; if (c3 > best) { best = c3; idx = 3; }
      float racc = l3bs[lane];
#pragma unroll
      for (int j = 0; j < 32; ++j) racc += xed[wv][j] * l3T[j * 17 + lane];
      const float* sxr = sx2l + idx * 16;
#pragma unroll
      for (int j = 0; j < 16; ++j) racc += sxr[j] * l3T[(32 + j) * 17 + lane];
      if (bf) ((__hip_bfloat16*)out)[n * 16 + lane] = __float2bfloat16(racc);
      else    ((float*)out)[n * 16 + lane] = racc;
    }
  }
}

extern "C" void kernel_launch(void* const* d_in, const int* in_sizes, int n_in,
                              void* d_out, int out_size, void* d_ws, size_t ws_size,
                              hipStream_t stream) {
  float* F = (float*)d_ws;
  int* I = (int*)d_ws;

  static const int pcnt[29] = {6400, 4096, 4096, 64, 4096, 4096, 64, 256, 256, 4, 528, 4,
                               4096, 4096, 64, 4096, 4096, 64, 4096, 4096, 64,
                               12288, 64, 1024, 16, 6144, 32, 768, 16};
  int poff[29];
  { int a = 0; for (int i = 0; i < 29; ++i) { poff[i] = a; a += pcnt[i]; } }

  PtrTab tab;
  for (int i = 0; i < 29; ++i) { tab.src[i] = d_in[i]; tab.off[i] = poff[i]; tab.cnt[i] = pcnt[i]; }

  const int* ei = (const int*)d_in[29];
  const int* nt = (const int*)d_in[30];

  int* deg = I + W_DEG;
  int* cur = I + W_CUR;
  int* rowptr = I + W_ROWPTR;
  int* col = I + W_COL;
  int* flag = I + W_FLAG;
  float* st = F + W_STATS;
  float* sxacc = F + W_SXACC;
  float* x0 = F + W_X0;
  float* zp1 = F + W_ZP1; float* zp2 = F + W_ZP2; float* zp3 = F + W_ZP3;
  float* ze1 = F + W_ZE1; float* ze2 = F + W_ZE2; float* ze3 = F + W_ZE3;
  float* sbuf = F + W_S;
  float* P = F + W_PAR;
#define PP(i) (P + poff[i])

  hipMemsetAsync(d_ws, 0, (size_t)W_ZEND * 4, stream);
  k_prelude<<<1154, 256, 0, stream>>>(tab, P, nt, x0, ei, deg, flag);
  k_scan<<<1, 1024, 0, stream>>>(deg, rowptr);
  k_scatter<<<750, 256, 0, stream>>>(ei, rowptr, cur, col);

  // layer 1 (pool & embed share input x0, no input BN)
  k_dual<64, 64, false><<<1024, 256, 0, stream>>>(
      x0, nullptr, PP(1), PP(2), PP(3), zp1, st + 0 * 128,
      x0, nullptr, PP(12), PP(13), PP(14), ze1, st + 3 * 128,
      rowptr, col, 512);
  // layer 2
  k_dual<64, 64, true><<<1024, 256, 0, stream>>>(
      zp1, st + 0 * 128, PP(4), PP(5), PP(6), zp2, st + 1 * 128,
      ze1, st + 3 * 128, PP(15), PP(16), PP(17), ze2, st + 4 * 128,
      rowptr, col, 512);
  // layer 3
  k_dual<4, 64, true><<<1024, 256, 0, stream>>>(
      zp2, st + 1 * 128, PP(7), PP(8), PP(9), zp3, st + 2 * 128,
      ze2, st + 4 * 128, PP(18), PP(19), PP(20), ze3, st + 5 * 128,
      rowptr, col, 512);

  k_pool<<<375, 256, 0, stream>>>(zp1, zp2, zp3, st + 0 * 128, st + 1 * 128, st + 2 * 128,
                                  ze1, ze2, ze3, st + 3 * 128, st + 4 * 128, st + 5 * 128,
                                  PP(10), PP(11), sbuf, sxacc);
  k_final<<<512, 256, 0, stream>>>(ze1, ze2, ze3, st + 3 * 128, st + 4 * 128, st + 5 * 128,
                                   PP(25), PP(26), PP(27), PP(28), sbuf,
                                   sxacc, PP(21), PP(22), PP(23), PP(24), flag, d_out);
}